// Round 7
// baseline (61.310 us; speedup 1.0000x reference)
//
#include <hip/hip_runtime.h>
#include <hip/hip_bf16.h>
#include <stdint.h>

typedef float f32x4 __attribute__((ext_vector_type(4)));
typedef __bf16 bf16x8 __attribute__((ext_vector_type(8)));
typedef unsigned short ushort8 __attribute__((ext_vector_type(8)));
typedef uint32_t u32x4 __attribute__((ext_vector_type(4)));

typedef const __attribute__((address_space(1))) uint32_t gu32;
typedef __attribute__((address_space(3))) uint32_t lu32;

#define N_TOK 128
#define OUT_F 8192
#define IN_F  8192
#define RANK  32

#define KSPLIT 16               // main-gemm k-split
#define KB    (IN_F / KSPLIT)   // 512 per block
#define ITERS (KB / 64)         // 8 K64 iterations
#define LKC   4                 // lora-t k-chunks

// workspace layout (bytes)
#define XB_OFF 0
#define TB_OFF ((size_t)N_TOK * IN_F * 2)                      // 2 MiB tile-ordered bf16 x
#define PO_OFF (TB_OFF + (size_t)LKC * N_TOK * RANK * 4)       // + 64 KiB t-partials
// pO: KSPLIT * 128 * 8192 bf16 = 32 MiB

__device__ __forceinline__ unsigned short bf16r(float f) {
    uint32_t u = __float_as_uint(f);
    return (unsigned short)((u + 0x7FFFu + ((u >> 16) & 1u)) >> 16);
}

__device__ __forceinline__ int swz(int row, int col) { return col ^ ((row & 7) << 3); }

// ---------------- kernel A: x fp32 -> bf16, GEMM-tile order, pre-swizzled ----------------
// xt chunk f = ((sblk*128 + r)*8 + c8) holds X(r, sblk*64 + ((c8 ^ (r&7))*8 + e);
// a linear global_load_lds then yields the XOR-swizzled LDS image readers expect.
__global__ __launch_bounds__(256) void cvt_x(const float* __restrict__ x,
                                             unsigned short* __restrict__ xt) {
    size_t f = (size_t)blockIdx.x * 256 + threadIdx.x;  // 0..131071
    int c8 = (int)(f & 7);
    int r = (int)((f >> 3) & 127);
    int sblk = (int)(f >> 10);  // 0..127
    int k = sblk * 64 + ((c8 ^ (r & 7)) << 3);
    const float4* sp = (const float4*)(x + (size_t)r * IN_F + k);
    float4 a = sp[0], b = sp[1];
    ushort8 o;
    o[0] = bf16r(a.x); o[1] = bf16r(a.y); o[2] = bf16r(a.z); o[3] = bf16r(a.w);
    o[4] = bf16r(b.x); o[5] = bf16r(b.y); o[6] = bf16r(b.z); o[7] = bf16r(b.w);
    *(ushort8*)(xt + f * 8) = o;
}

// ---------------- kernel B: t-partials = x @ lora_B^T, coalesced ----------------
__global__ __launch_bounds__(256) void lora_t(const float* __restrict__ x,
                                              const float* __restrict__ lb,
                                              float* __restrict__ tB) {
    __shared__ float ts[256][33];
    __shared__ float ps[8][32];
    const int m = blockIdx.x >> 2, kc = blockIdx.x & 3;
    const int tid = threadIdx.x;
    const int c0 = kc * 2048 + tid * 8;
    float4 xv0 = *(const float4*)(x + (size_t)m * IN_F + c0);
    float4 xv1 = *(const float4*)(x + (size_t)m * IN_F + c0 + 4);
#pragma unroll
    for (int r = 0; r < RANK; ++r) {
        const float4* bp = (const float4*)(lb + (size_t)r * IN_F + c0);
        float4 b0 = bp[0], b1 = bp[1];
        float s = xv0.x * b0.x + xv0.y * b0.y + xv0.z * b0.z + xv0.w * b0.w +
                  xv1.x * b1.x + xv1.y * b1.y + xv1.z * b1.z + xv1.w * b1.w;
        ts[tid][r] = s;
    }
    __syncthreads();
    {
        int g = tid >> 5, r = tid & 31;
        float s = 0.f;
        for (int j = 0; j < 32; ++j) s += ts[g * 32 + j][r];
        ps[g][r] = s;
    }
    __syncthreads();
    if (tid < 32) {
        float s = 0.f;
#pragma unroll
        for (int g = 0; g < 8; ++g) s += ps[g][tid];
        tB[(kc * N_TOK + m) * RANK + tid] = s;
    }
}

// ---------------- decode: 8 ternary codes (2 widened ints) -> 4 dwords of bf16 pairs ----------------
__device__ __forceinline__ u32x4 decode8(int2 v) {
    uint32_t p = (uint32_t)(v.x & 0xFF) | (((uint32_t)(v.y & 0xFF)) << 8);
    const uint32_t HI = 0x403F00BFu;  // {-1:BF80, 0:0000, +1:3F80}
    const uint32_t LO = 0x00800080u;
    u32x4 d;
#pragma unroll
    for (int j = 0; j < 4; ++j) {
        uint32_t c0 = (p >> (4 * j)) & 3u;
        uint32_t c1 = (p >> (4 * j + 2)) & 3u;
        uint32_t t = c0 | (c1 << 16);
        uint32_t sel = (t | (t << 8)) + 0x04000400u;
        d[j] = __builtin_amdgcn_perm(HI, LO, sel);
    }
    return d;
}

// ---------------- kernel C: ternary GEMM — W in registers, x LDS dbuf DMA ----------------
// grid = 64 n-tiles * KSPLIT(16) = 1024 blocks; 4 waves; wave tile M=128 x N=32.
__global__ __launch_bounds__(256, 3) void ternary_gemm(const unsigned short* __restrict__ xt,
                                                       const int* __restrict__ wp,
                                                       unsigned short* __restrict__ pO) {
    __shared__ unsigned short xs[2][128][64];  // 2 x 16 KiB only
    const int tid = threadIdx.x;
    const int nb = blockIdx.x >> 4;
    const int ks = blockIdx.x & 15;
    const int n0 = nb * 128;
    const int lane = tid & 63;
    const int wid = tid >> 6;
    const int arow = lane & 15;
    const int kq = lane >> 4;            // 0..3, k-offset = kq*8

    // W pointers: frag br (0,1): row = n0 + wid*32 + br*16 + arow
    const int* pw0 = wp + (size_t)(n0 + wid * 32 + arow) * (IN_F / 4) + ks * (KB / 4) + kq * 2;
    const int* pw1 = pw0 + (size_t)16 * (IN_F / 4);
    // per (it, kk): int2 at pw{br} + it*16 + kk*8

    // x DMA source (pre-swizzled tile order): per it, 16 KiB at sblk = ks*ITERS + it
    const unsigned short* xsrc = xt + ((size_t)(ks * ITERS) * 128 + wid * 8) * 64 + lane * 8;

    f32x4 acc[8][2];
#pragma unroll
    for (int i = 0; i < 8; ++i) { acc[i][0] = (f32x4){0,0,0,0}; acc[i][1] = (f32x4){0,0,0,0}; }

    // ---- prologue: DMA x(0); W sets for it=0 (A) and it=1 (B) ----
#pragma unroll
    for (int j = 0; j < 4; ++j)
        __builtin_amdgcn_global_load_lds(
            (gu32*)(xsrc + j * 2048),
            (lu32*)((char*)(&xs[0][0][0]) + wid * 1024 + j * 4096), 16, 0, 0);
    int2 wA0 = *(const int2*)(pw0);          // it0 kk0 frag0
    int2 wA1 = *(const int2*)(pw0 + 8);      // it0 kk1 frag0
    int2 wA2 = *(const int2*)(pw1);          // it0 kk0 frag1
    int2 wA3 = *(const int2*)(pw1 + 8);      // it0 kk1 frag1
    int2 wB0 = *(const int2*)(pw0 + 16);
    int2 wB1 = *(const int2*)(pw0 + 24);
    int2 wB2 = *(const int2*)(pw1 + 16);
    int2 wB3 = *(const int2*)(pw1 + 24);
    __syncthreads();

#pragma unroll
    for (int it = 0; it < ITERS; ++it) {
        const int cur = it & 1;
        // DMA x(it+1) into the buffer consumed last iter
        if (it + 1 < ITERS) {
#pragma unroll
            for (int j = 0; j < 4; ++j)
                __builtin_amdgcn_global_load_lds(
                    (gu32*)(xsrc + (size_t)(it + 1) * 8192 + j * 2048),
                    (lu32*)((char*)(&xs[cur ^ 1][0][0]) + wid * 1024 + j * 4096), 16, 0, 0);
        }
        // decode this iter's set fully into registers
        u32x4 dk0f0, dk0f1, dk1f0, dk1f1;
        if ((it & 1) == 0) {
            dk0f0 = decode8(wA0); dk1f0 = decode8(wA1);
            dk0f1 = decode8(wA2); dk1f1 = decode8(wA3);
            if (it + 2 < ITERS) {  // refill set A for it+2
                wA0 = *(const int2*)(pw0 + (it + 2) * 16);
                wA1 = *(const int2*)(pw0 + (it + 2) * 16 + 8);
                wA2 = *(const int2*)(pw1 + (it + 2) * 16);
                wA3 = *(const int2*)(pw1 + (it + 2) * 16 + 8);
            }
        } else {
            dk0f0 = decode8(wB0); dk1f0 = decode8(wB1);
            dk0f1 = decode8(wB2); dk1f1 = decode8(wB3);
            if (it + 2 < ITERS) {  // refill set B for it+2
                wB0 = *(const int2*)(pw0 + (it + 2) * 16);
                wB1 = *(const int2*)(pw0 + (it + 2) * 16 + 8);
                wB2 = *(const int2*)(pw1 + (it + 2) * 16);
                wB3 = *(const int2*)(pw1 + (it + 2) * 16 + 8);
            }
        }
        bf16x8 b00 = __builtin_bit_cast(bf16x8, dk0f0);
        bf16x8 b01 = __builtin_bit_cast(bf16x8, dk0f1);
        bf16x8 b10 = __builtin_bit_cast(bf16x8, dk1f0);
        bf16x8 b11 = __builtin_bit_cast(bf16x8, dk1f1);
        // kk = 0
        {
            const int kcol = kq * 8;
#pragma unroll
            for (int ar = 0; ar < 8; ++ar) {
                int row = ar * 16 + arow;
                bf16x8 af = *(const bf16x8*)&xs[cur][row][swz(row, kcol)];
                acc[ar][0] = __builtin_amdgcn_mfma_f32_16x16x32_bf16(af, b00, acc[ar][0], 0, 0, 0);
                acc[ar][1] = __builtin_amdgcn_mfma_f32_16x16x32_bf16(af, b01, acc[ar][1], 0, 0, 0);
            }
        }
        // kk = 1
        {
            const int kcol = 32 + kq * 8;
#pragma unroll
            for (int ar = 0; ar < 8; ++ar) {
                int row = ar * 16 + arow;
                bf16x8 af = *(const bf16x8*)&xs[cur][row][swz(row, kcol)];
                acc[ar][0] = __builtin_amdgcn_mfma_f32_16x16x32_bf16(af, b10, acc[ar][0], 0, 0, 0);
                acc[ar][1] = __builtin_amdgcn_mfma_f32_16x16x32_bf16(af, b11, acc[ar][1], 0, 0, 0);
            }
        }
        __syncthreads();
    }

    // epilogue: bf16 partial store
    unsigned short* po = pO + ((size_t)ks << 20);
    const int mrow = kq * 4;
#pragma unroll
    for (int ar = 0; ar < 8; ++ar) {
#pragma unroll
        for (int br = 0; br < 2; ++br) {
            int m = ar * 16 + mrow;
            int n = n0 + wid * 32 + br * 16 + arow;
            unsigned short* pp = po + (size_t)m * OUT_F + n;
#pragma unroll
            for (int j = 0; j < 4; ++j) pp[(size_t)j * OUT_F] = bf16r(acc[ar][br][j]);
        }
    }
}

// ---------------- kernel D: reduce bf16 partials + scale + lora + bias ----------------
// grid = 16 nb * 32 mg = 512 blocks; thread: 2 consecutive n, 4 m's
__global__ __launch_bounds__(256) void reduce_out(const unsigned short* __restrict__ pO,
                                                  const float* __restrict__ tB,
                                                  const float* __restrict__ scale,
                                                  const float* __restrict__ lora_A,
                                                  const float* __restrict__ bias,
                                                  float* __restrict__ out) {
    __shared__ float ts[4][RANK];
    int nb = blockIdx.x & 15, mg = blockIdx.x >> 4;
    int tid = threadIdx.x;
    int m0 = mg * 4;
    if (tid < 128) {
        int i = tid >> 5, r = tid & 31;
        float s = 0.f;
#pragma unroll
        for (int c = 0; c < LKC; ++c) s += tB[(c * N_TOK + m0 + i) * RANK + r];
        ts[i][r] = s;
    }
    __syncthreads();
    int n = nb * 512 + tid * 2;
    float sc0 = scale[n], sc1 = scale[n + 1];
    float bs0 = bias[n], bs1 = bias[n + 1];
    float4 a0[8], a1[8];
    const float4* ap0 = (const float4*)(lora_A + (size_t)n * RANK);
    const float4* ap1 = (const float4*)(lora_A + (size_t)(n + 1) * RANK);
#pragma unroll
    for (int q = 0; q < 8; ++q) { a0[q] = ap0[q]; a1[q] = ap1[q]; }
#pragma unroll
    for (int i = 0; i < 4; ++i) {
        int m = m0 + i;
        const unsigned short* pp = pO + (size_t)m * OUT_F + n;
        float s0 = 0.f, s1 = 0.f;
#pragma unroll
        for (int c = 0; c < KSPLIT; ++c) {
            uint32_t u = *(const uint32_t*)(pp + ((size_t)c << 20));
            s0 += __uint_as_float(u << 16);
            s1 += __uint_as_float(u & 0xFFFF0000u);
        }
        float l0 = 0.f, l1 = 0.f;
#pragma unroll
        for (int q = 0; q < 8; ++q) {
            float4 tv = *(const float4*)&ts[i][q * 4];
            l0 = fmaf(tv.x, a0[q].x, l0); l0 = fmaf(tv.y, a0[q].y, l0);
            l0 = fmaf(tv.z, a0[q].z, l0); l0 = fmaf(tv.w, a0[q].w, l0);
            l1 = fmaf(tv.x, a1[q].x, l1); l1 = fmaf(tv.y, a1[q].y, l1);
            l1 = fmaf(tv.z, a1[q].z, l1); l1 = fmaf(tv.w, a1[q].w, l1);
        }
        out[(size_t)m * OUT_F + n]     = fmaf(s0, sc0, l0 + bs0);
        out[(size_t)m * OUT_F + n + 1] = fmaf(s1, sc1, l1 + bs1);
    }
}

extern "C" void kernel_launch(void* const* d_in, const int* in_sizes, int n_in,
                              void* d_out, int out_size, void* d_ws, size_t ws_size,
                              hipStream_t stream) {
    const float* x      = (const float*)d_in[0];
    const int*   wp     = (const int*)d_in[1];   // uint8 input -> int32 on device
    const float* scale  = (const float*)d_in[2];
    const float* lora_A = (const float*)d_in[3];
    const float* lora_B = (const float*)d_in[4];
    const float* bias   = (const float*)d_in[5];
    float* out = (float*)d_out;

    char* ws = (char*)d_ws;
    unsigned short* xt = (unsigned short*)(ws + XB_OFF);
    float* tB = (float*)(ws + TB_OFF);
    unsigned short* pO = (unsigned short*)(ws + PO_OFF);

    cvt_x<<<512, 256, 0, stream>>>(x, xt);
    lora_t<<<N_TOK * LKC, 256, 0, stream>>>(x, lora_B, tB);
    ternary_gemm<<<(OUT_F / 128) * KSPLIT, 256, 0, stream>>>(xt, wp, pO);
    reduce_out<<<16 * 32, 256, 0, stream>>>(pO, tB, scale, lora_A, bias, out);
}

// Round 8
// 52.776 us; speedup vs baseline: 1.1617x; 1.1617x over previous
//
#include <hip/hip_runtime.h>
#include <hip/hip_bf16.h>
#include <stdint.h>

typedef float f32x4 __attribute__((ext_vector_type(4)));
typedef __bf16 bf16x8 __attribute__((ext_vector_type(8)));
typedef unsigned short ushort8 __attribute__((ext_vector_type(8)));

typedef const __attribute__((address_space(1))) uint32_t gu32;
typedef __attribute__((address_space(3))) uint32_t lu32;

#define N_TOK 128
#define OUT_F 8192
#define IN_F  8192
#define RANK  32

#define KSPLIT 8                // main-gemm k-split
#define KB    (IN_F / KSPLIT)   // 1024 per block
#define BK    64
#define NSTEP (KB / BK)         // 16
#define WSTRIDE 16              // ints per step per W row (BK/4)
#define LKC   4                 // lora-t k-chunks

// workspace layout (bytes)
#define XB_OFF 0
#define TB_OFF ((size_t)N_TOK * IN_F * 2)                      // 2 MiB tile-ordered bf16 x
#define PO_OFF (TB_OFF + (size_t)LKC * N_TOK * RANK * 4)       // + 64 KiB t-partials
// pO: KSPLIT * 128 * 8192 bf16 = 16 MiB

__device__ __forceinline__ unsigned short bf16r(float f) {
    uint32_t u = __float_as_uint(f);
    return (unsigned short)((u + 0x7FFFu + ((u >> 16) & 1u)) >> 16);
}

__device__ __forceinline__ int swz(int row, int col) { return col ^ ((row & 7) << 3); }

// ---------------- kernel A: x fp32 -> bf16, GEMM-tile order, pre-swizzled ----------------
// xt chunk f = ((sblk*128 + r)*8 + c8) holds X(r, sblk*64 + ((c8 ^ (r&7))*8 + e);
// a linear global_load_lds then yields the XOR-swizzled LDS image readers expect.
__global__ __launch_bounds__(256) void cvt_x(const float* __restrict__ x,
                                             unsigned short* __restrict__ xt) {
    size_t f = (size_t)blockIdx.x * 256 + threadIdx.x;  // 0..131071
    int c8 = (int)(f & 7);
    int r = (int)((f >> 3) & 127);
    int sblk = (int)(f >> 10);  // 0..127
    int k = sblk * 64 + ((c8 ^ (r & 7)) << 3);
    const float4* sp = (const float4*)(x + (size_t)r * IN_F + k);
    float4 a = sp[0], b = sp[1];
    ushort8 o;
    o[0] = bf16r(a.x); o[1] = bf16r(a.y); o[2] = bf16r(a.z); o[3] = bf16r(a.w);
    o[4] = bf16r(b.x); o[5] = bf16r(b.y); o[6] = bf16r(b.z); o[7] = bf16r(b.w);
    *(ushort8*)(xt + f * 8) = o;
}

// ---------------- kernel B: t-partials = x @ lora_B^T, coalesced ----------------
__global__ __launch_bounds__(256) void lora_t(const float* __restrict__ x,
                                              const float* __restrict__ lb,
                                              float* __restrict__ tB) {
    __shared__ float ts[256][33];
    __shared__ float ps[8][32];
    const int m = blockIdx.x >> 2, kc = blockIdx.x & 3;
    const int tid = threadIdx.x;
    const int c0 = kc * 2048 + tid * 8;
    float4 xv0 = *(const float4*)(x + (size_t)m * IN_F + c0);
    float4 xv1 = *(const float4*)(x + (size_t)m * IN_F + c0 + 4);
#pragma unroll
    for (int r = 0; r < RANK; ++r) {
        const float4* bp = (const float4*)(lb + (size_t)r * IN_F + c0);
        float4 b0 = bp[0], b1 = bp[1];
        float s = xv0.x * b0.x + xv0.y * b0.y + xv0.z * b0.z + xv0.w * b0.w +
                  xv1.x * b1.x + xv1.y * b1.y + xv1.z * b1.z + xv1.w * b1.w;
        ts[tid][r] = s;
    }
    __syncthreads();
    {
        int g = tid >> 5, r = tid & 31;
        float s = 0.f;
        for (int j = 0; j < 32; ++j) s += ts[g * 32 + j][r];
        ps[g][r] = s;
    }
    __syncthreads();
    if (tid < 32) {
        float s = 0.f;
#pragma unroll
        for (int g = 0; g < 8; ++g) s += ps[g][tid];
        tB[(kc * N_TOK + m) * RANK + tid] = s;
    }
}

// ---------------- decode: 16 ternary codes (4 widened ints) -> 8 dwords of bf16 pairs ----------------
__device__ __forceinline__ void decodeW(int4 v, uint32_t d[8]) {
    uint32_t p = (uint32_t)v.x | ((uint32_t)v.y << 8) |
                 ((uint32_t)v.z << 16) | ((uint32_t)v.w << 24);
    const uint32_t HI = 0x403F00BFu;
    const uint32_t LO = 0x00800080u;
#pragma unroll
    for (int j = 0; j < 8; ++j) {
        uint32_t c0 = (p >> (4 * j)) & 3u;
        uint32_t c1 = (p >> (4 * j + 2)) & 3u;
        uint32_t t = c0 | (c1 << 16);
        uint32_t sel = (t | (t << 8)) + 0x04000400u;
        d[j] = __builtin_amdgcn_perm(HI, LO, sel);
    }
}

// ---------------- kernel C: ternary GEMM, counted-vmcnt pipeline, 1 raw barrier/step ----------------
// grid = 64 n-tiles * KSPLIT(8) = 512 blocks, 256 threads (4 waves, 2x2 of 64x64).
// vmem FIFO per iter (issue-order pinned by sched_barrier): DMA(s+1) x4, W(s+2) x2.
// Bottom wait: vmcnt(2) -> DMA retired, W loads ride across the barrier (T4).
__global__ __launch_bounds__(256) void ternary_gemm(const unsigned short* __restrict__ xt,
                                                    const int* __restrict__ wp,
                                                    unsigned short* __restrict__ pO) {
    __shared__ unsigned short xs[2][128][64];  // 2 x 16 KiB, DMA'd linear (pre-swizzled src)
    __shared__ unsigned short ww[2][128][64];  // 2 x 16 KiB, decoded + XOR-swizzled writes
    const int tid = threadIdx.x;
    const int nb = blockIdx.x >> 3;
    const int ks = blockIdx.x & 7;
    const int n0 = nb * 128;
    const int lane = tid & 63;
    const int wid = tid >> 6;
    const int wr = wid >> 1, wc = wid & 1;

    const int srow = tid >> 2;
    const int xcol = (tid & 3) * 16;
    const int* pg0 = wp + (size_t)(n0 + srow) * (IN_F / 4) + ks * (KB / 4) + (tid & 3) * 4;
    const int* pg1 = pg0 + (size_t)64 * (IN_F / 4);

    const unsigned short* xsrc = xt + ((size_t)(ks * NSTEP) * 128 + wid * 8) * 64 + lane * 8;

    f32x4 acc[4][4];
#pragma unroll
    for (int i = 0; i < 4; ++i)
#pragma unroll
        for (int j = 0; j < 4; ++j) acc[i][j] = (f32x4){0.f, 0.f, 0.f, 0.f};

    const int arow = lane & 15;
    const int kgrp = (lane >> 4) * 8;
    const int wc0 = swz(srow, xcol), wc1 = swz(srow, xcol + 8);

    // ---------- prologue ----------
    // issue order: DMA(0) x4 | W(0) x2 | W(1) x2
#pragma unroll
    for (int j = 0; j < 4; ++j)
        __builtin_amdgcn_global_load_lds(
            (gu32*)(xsrc + j * 2048),
            (lu32*)((char*)(&xs[0][0][0]) + wid * 1024 + j * 4096), 16, 0, 0);
    __builtin_amdgcn_sched_barrier(0);
    int4 wA0 = *(const int4*)(pg0);           // W(0) -> set A (even)
    int4 wA1 = *(const int4*)(pg1);
    __builtin_amdgcn_sched_barrier(0);
    int4 wB0 = *(const int4*)(pg0 + WSTRIDE); // W(1) -> set B (odd)
    int4 wB1 = *(const int4*)(pg1 + WSTRIDE);
    __builtin_amdgcn_sched_barrier(0);
    {
        uint32_t d0[8], d1[8];
        decodeW(wA0, d0);                     // compiler waits: retires DMA(0)+W(0)
        decodeW(wA1, d1);
        *(uint4*)&ww[0][srow][wc0]      = make_uint4(d0[0], d0[1], d0[2], d0[3]);
        *(uint4*)&ww[0][srow][wc1]      = make_uint4(d0[4], d0[5], d0[6], d0[7]);
        *(uint4*)&ww[0][srow + 64][wc0] = make_uint4(d1[0], d1[1], d1[2], d1[3]);
        *(uint4*)&ww[0][srow + 64][wc1] = make_uint4(d1[4], d1[5], d1[6], d1[7]);
    }
    __builtin_amdgcn_sched_barrier(0);
    asm volatile("s_waitcnt lgkmcnt(0)" ::: "memory");   // ds_writes visible; W(1) rides
    __builtin_amdgcn_s_barrier();
    __builtin_amdgcn_sched_barrier(0);

#pragma unroll
    for (int s = 0; s < NSTEP; ++s) {
        const int cur = s & 1, nxt = cur ^ 1;
        // A: DMA x(s+1) -> xs[nxt]  (all waves passed barrier: xs[nxt] consumed)
        if (s + 1 < NSTEP) {
#pragma unroll
            for (int j = 0; j < 4; ++j)
                __builtin_amdgcn_global_load_lds(
                    (gu32*)(xsrc + (size_t)(s + 1) * 8192 + j * 2048),
                    (lu32*)((char*)(&xs[nxt][0][0]) + wid * 1024 + j * 4096), 16, 0, 0);
        }
        __builtin_amdgcn_sched_barrier(0);
        // B: issue W(s+2) into set parity (s+2)&1 == s&1
        if (s + 2 < NSTEP) {
            if ((s & 1) == 0) {
                wA0 = *(const int4*)(pg0 + (s + 2) * WSTRIDE);
                wA1 = *(const int4*)(pg1 + (s + 2) * WSTRIDE);
            } else {
                wB0 = *(const int4*)(pg0 + (s + 2) * WSTRIDE);
                wB1 = *(const int4*)(pg1 + (s + 2) * WSTRIDE);
            }
        }
        __builtin_amdgcn_sched_barrier(0);
        // C: decode W(s+1) (parity (s+1)&1) -> ww[nxt]
        if (s + 1 < NSTEP) {
            uint32_t d0[8], d1[8];
            if ((s & 1) == 0) { decodeW(wB0, d0); decodeW(wB1, d1); }
            else              { decodeW(wA0, d0); decodeW(wA1, d1); }
            *(uint4*)&ww[nxt][srow][wc0]      = make_uint4(d0[0], d0[1], d0[2], d0[3]);
            *(uint4*)&ww[nxt][srow][wc1]      = make_uint4(d0[4], d0[5], d0[6], d0[7]);
            *(uint4*)&ww[nxt][srow + 64][wc0] = make_uint4(d1[0], d1[1], d1[2], d1[3]);
            *(uint4*)&ww[nxt][srow + 64][wc1] = make_uint4(d1[4], d1[5], d1[6], d1[7]);
        }
        // D: MFMA on cur buffers
#pragma unroll
        for (int kk = 0; kk < 2; ++kk) {
            const int kcol = kk * 32 + kgrp;
            bf16x8 af[4], bfr[4];
#pragma unroll
            for (int ar = 0; ar < 4; ++ar) {
                int row = wr * 64 + ar * 16 + arow;
                af[ar] = *(const bf16x8*)&xs[cur][row][swz(row, kcol)];
            }
#pragma unroll
            for (int br = 0; br < 4; ++br) {
                int row = wc * 64 + br * 16 + arow;
                bfr[br] = *(const bf16x8*)&ww[cur][row][swz(row, kcol)];
            }
#pragma unroll
            for (int ar = 0; ar < 4; ++ar)
#pragma unroll
                for (int br = 0; br < 4; ++br)
                    acc[ar][br] = __builtin_amdgcn_mfma_f32_16x16x32_bf16(
                        af[ar], bfr[br], acc[ar][br], 0, 0, 0);
        }
        // E/F: counted wait + raw barrier (skip after last iter)
        if (s + 1 < NSTEP) {
            __builtin_amdgcn_sched_barrier(0);
            if (s + 2 < NSTEP) {
                // outstanding: DMA(s+1) x4 (oldest) + W(s+2) x2 -> retire DMA only
                asm volatile("s_waitcnt vmcnt(2) lgkmcnt(0)" ::: "memory");
            } else {
                // no W issued this iter: retire DMA fully
                asm volatile("s_waitcnt vmcnt(0) lgkmcnt(0)" ::: "memory");
            }
            __builtin_amdgcn_s_barrier();
            __builtin_amdgcn_sched_barrier(0);
        }
    }

    // epilogue: bf16 partial store
    unsigned short* po = pO + ((size_t)ks << 20);
    const int mrow = (lane >> 4) * 4;
#pragma unroll
    for (int ar = 0; ar < 4; ++ar) {
#pragma unroll
        for (int br = 0; br < 4; ++br) {
            int m = wr * 64 + ar * 16 + mrow;
            int n = n0 + wc * 64 + br * 16 + arow;
            unsigned short* pp = po + (size_t)m * OUT_F + n;
#pragma unroll
            for (int j = 0; j < 4; ++j) pp[(size_t)j * OUT_F] = bf16r(acc[ar][br][j]);
        }
    }
}

// ---------------- kernel D: reduce bf16 partials + scale + lora + bias ----------------
// grid = 16 nb * 32 mg = 512 blocks; thread: 2 consecutive n, 4 m's
__global__ __launch_bounds__(256) void reduce_out(const unsigned short* __restrict__ pO,
                                                  const float* __restrict__ tB,
                                                  const float* __restrict__ scale,
                                                  const float* __restrict__ lora_A,
                                                  const float* __restrict__ bias,
                                                  float* __restrict__ out) {
    __shared__ float ts[4][RANK];
    int nb = blockIdx.x & 15, mg = blockIdx.x >> 4;
    int tid = threadIdx.x;
    int m0 = mg * 4;
    if (tid < 128) {
        int i = tid >> 5, r = tid & 31;
        float s = 0.f;
#pragma unroll
        for (int c = 0; c < LKC; ++c) s += tB[(c * N_TOK + m0 + i) * RANK + r];
        ts[i][r] = s;
    }
    __syncthreads();
    int n = nb * 512 + tid * 2;
    float sc0 = scale[n], sc1 = scale[n + 1];
    float bs0 = bias[n], bs1 = bias[n + 1];
    float4 a0[8], a1[8];
    const float4* ap0 = (const float4*)(lora_A + (size_t)n * RANK);
    const float4* ap1 = (const float4*)(lora_A + (size_t)(n + 1) * RANK);
#pragma unroll
    for (int q = 0; q < 8; ++q) { a0[q] = ap0[q]; a1[q] = ap1[q]; }
#pragma unroll
    for (int i = 0; i < 4; ++i) {
        int m = m0 + i;
        const unsigned short* pp = pO + (size_t)m * OUT_F + n;
        float s0 = 0.f, s1 = 0.f;
#pragma unroll
        for (int c = 0; c < KSPLIT; ++c) {
            uint32_t u = *(const uint32_t*)(pp + ((size_t)c << 20));
            s0 += __uint_as_float(u << 16);
            s1 += __uint_as_float(u & 0xFFFF0000u);
        }
        float l0 = 0.f, l1 = 0.f;
#pragma unroll
        for (int q = 0; q < 8; ++q) {
            float4 tv = *(const float4*)&ts[i][q * 4];
            l0 = fmaf(tv.x, a0[q].x, l0); l0 = fmaf(tv.y, a0[q].y, l0);
            l0 = fmaf(tv.z, a0[q].z, l0); l0 = fmaf(tv.w, a0[q].w, l0);
            l1 = fmaf(tv.x, a1[q].x, l1); l1 = fmaf(tv.y, a1[q].y, l1);
            l1 = fmaf(tv.z, a1[q].z, l1); l1 = fmaf(tv.w, a1[q].w, l1);
        }
        out[(size_t)m * OUT_F + n]     = fmaf(s0, sc0, l0 + bs0);
        out[(size_t)m * OUT_F + n + 1] = fmaf(s1, sc1, l1 + bs1);
    }
}

extern "C" void kernel_launch(void* const* d_in, const int* in_sizes, int n_in,
                              void* d_out, int out_size, void* d_ws, size_t ws_size,
                              hipStream_t stream) {
    const float* x      = (const float*)d_in[0];
    const int*   wp     = (const int*)d_in[1];   // uint8 input -> int32 on device
    const float* scale  = (const float*)d_in[2];
    const float* lora_A = (const float*)d_in[3];
    const float* lora_B = (const float*)d_in[4];
    const float* bias   = (const float*)d_in[5];
    float* out = (float*)d_out;

    char* ws = (char*)d_ws;
    unsigned short* xt = (unsigned short*)(ws + XB_OFF);
    float* tB = (float*)(ws + TB_OFF);
    unsigned short* pO = (unsigned short*)(ws + PO_OFF);

    cvt_x<<<512, 256, 0, stream>>>(x, xt);
    lora_t<<<N_TOK * LKC, 256, 0, stream>>>(x, lora_B, tB);
    ternary_gemm<<<(OUT_F / 128) * KSPLIT, 256, 0, stream>>>(xt, wp, pO);
    reduce_out<<<16 * 32, 256, 0, stream>>>(pO, tB, scale, lora_A, bias, out);
}

// Round 9
// 51.564 us; speedup vs baseline: 1.1890x; 1.0235x over previous
//
#include <hip/hip_runtime.h>
#include <hip/hip_bf16.h>
#include <stdint.h>

typedef float f32x4 __attribute__((ext_vector_type(4)));
typedef __bf16 bf16x8 __attribute__((ext_vector_type(8)));
typedef unsigned short ushort8 __attribute__((ext_vector_type(8)));

typedef const __attribute__((address_space(1))) uint32_t gu32;
typedef __attribute__((address_space(3))) uint32_t lu32;

#define N_TOK 128
#define OUT_F 8192
#define IN_F  8192
#define RANK  32

#define KSPLIT 8                // main-gemm k-split
#define KB    (IN_F / KSPLIT)   // 1024 per block
#define BK    64
#define NSTEP (KB / BK)         // 16
#define WSTRIDE 16              // ints per step per W row (BK/4)
#define LKC   4                 // lora-t k-chunks

// workspace layout (bytes)
#define XB_OFF 0
#define TB_OFF ((size_t)N_TOK * IN_F * 2)                      // 2 MiB tile-ordered bf16 x
#define PO_OFF (TB_OFF + (size_t)LKC * N_TOK * RANK * 4)       // + 64 KiB t-partials
// pO: KSPLIT * 128 * 8192 bf16 = 16 MiB

__device__ __forceinline__ unsigned short bf16r(float f) {
    uint32_t u = __float_as_uint(f);
    return (unsigned short)((u + 0x7FFFu + ((u >> 16) & 1u)) >> 16);
}

__device__ __forceinline__ int swz(int row, int col) { return col ^ ((row & 7) << 3); }

// ---------------- kernel A: x fp32 -> bf16, GEMM-tile order, pre-swizzled ----------------
__global__ __launch_bounds__(256) void cvt_x(const float* __restrict__ x,
                                             unsigned short* __restrict__ xt) {
    size_t f = (size_t)blockIdx.x * 256 + threadIdx.x;  // 0..131071
    int c8 = (int)(f & 7);
    int r = (int)((f >> 3) & 127);
    int sblk = (int)(f >> 10);  // 0..127
    int k = sblk * 64 + ((c8 ^ (r & 7)) << 3);
    const float4* sp = (const float4*)(x + (size_t)r * IN_F + k);
    float4 a = sp[0], b = sp[1];
    ushort8 o;
    o[0] = bf16r(a.x); o[1] = bf16r(a.y); o[2] = bf16r(a.z); o[3] = bf16r(a.w);
    o[4] = bf16r(b.x); o[5] = bf16r(b.y); o[6] = bf16r(b.z); o[7] = bf16r(b.w);
    *(ushort8*)(xt + f * 8) = o;
}

// ---------------- kernel B: t-partials = x @ lora_B^T, coalesced ----------------
__global__ __launch_bounds__(256) void lora_t(const float* __restrict__ x,
                                              const float* __restrict__ lb,
                                              float* __restrict__ tB) {
    __shared__ float ts[256][33];
    __shared__ float ps[8][32];
    const int m = blockIdx.x >> 2, kc = blockIdx.x & 3;
    const int tid = threadIdx.x;
    const int c0 = kc * 2048 + tid * 8;
    float4 xv0 = *(const float4*)(x + (size_t)m * IN_F + c0);
    float4 xv1 = *(const float4*)(x + (size_t)m * IN_F + c0 + 4);
#pragma unroll
    for (int r = 0; r < RANK; ++r) {
        const float4* bp = (const float4*)(lb + (size_t)r * IN_F + c0);
        float4 b0 = bp[0], b1 = bp[1];
        float s = xv0.x * b0.x + xv0.y * b0.y + xv0.z * b0.z + xv0.w * b0.w +
                  xv1.x * b1.x + xv1.y * b1.y + xv1.z * b1.z + xv1.w * b1.w;
        ts[tid][r] = s;
    }
    __syncthreads();
    {
        int g = tid >> 5, r = tid & 31;
        float s = 0.f;
        for (int j = 0; j < 32; ++j) s += ts[g * 32 + j][r];
        ps[g][r] = s;
    }
    __syncthreads();
    if (tid < 32) {
        float s = 0.f;
#pragma unroll
        for (int g = 0; g < 8; ++g) s += ps[g][tid];
        tB[(kc * N_TOK + m) * RANK + tid] = s;
    }
}

// ---------------- decode: 16 ternary codes (4 widened ints) -> 8 dwords of bf16 pairs ----------------
__device__ __forceinline__ void decodeW(int4 v, uint32_t d[8]) {
    uint32_t p = (uint32_t)v.x | ((uint32_t)v.y << 8) |
                 ((uint32_t)v.z << 16) | ((uint32_t)v.w << 24);
    const uint32_t HI = 0x403F00BFu;
    const uint32_t LO = 0x00800080u;
#pragma unroll
    for (int j = 0; j < 8; ++j) {
        uint32_t c0 = (p >> (4 * j)) & 3u;
        uint32_t c1 = (p >> (4 * j + 2)) & 3u;
        uint32_t t = c0 | (c1 << 16);
        uint32_t sel = (t | (t << 8)) + 0x04000400u;
        d[j] = __builtin_amdgcn_perm(HI, LO, sel);
    }
}

// ---------------- kernel C: ternary GEMM, deep pipeline ----------------
// x: ring-3 LDS via global_load_lds, DMA(s+2) issued at step s (~1.8-step cover).
// W: ring-4 register sets, W(s+4) loaded at step s, decoded at s+3 (3-step cover).
// One raw s_barrier per step; counted vmcnt (steady N=8) so loads ride across it.
// grid = 64 n-tiles * KSPLIT(8) = 512 blocks, 256 threads (4 waves, 2x2 of 64x64).
__global__ __launch_bounds__(256) void ternary_gemm(const unsigned short* __restrict__ xt,
                                                    const int* __restrict__ wp,
                                                    unsigned short* __restrict__ pO) {
    __shared__ unsigned short xs[3][128][64];  // 3 x 16 KiB, DMA'd linear (pre-swizzled src)
    __shared__ unsigned short ww[2][128][64];  // 2 x 16 KiB, decoded + XOR-swizzled writes
    const int tid = threadIdx.x;
    const int nb = blockIdx.x >> 3;
    const int ks = blockIdx.x & 7;
    const int n0 = nb * 128;
    const int lane = tid & 63;
    const int wid = tid >> 6;
    const int wr = wid >> 1, wc = wid & 1;

    const int srow = tid >> 2;
    const int xcol = (tid & 3) * 16;
    const int* pg0 = wp + (size_t)(n0 + srow) * (IN_F / 4) + ks * (KB / 4) + (tid & 3) * 4;
    const int* pg1 = pg0 + (size_t)64 * (IN_F / 4);

    const unsigned short* xsrc = xt + ((size_t)(ks * NSTEP) * 128 + wid * 8) * 64 + lane * 8;

    f32x4 acc[4][4];
#pragma unroll
    for (int i = 0; i < 4; ++i)
#pragma unroll
        for (int j = 0; j < 4; ++j) acc[i][j] = (f32x4){0.f, 0.f, 0.f, 0.f};

    const int arow = lane & 15;
    const int kgrp = (lane >> 4) * 8;
    const int wc0 = swz(srow, xcol), wc1 = swz(srow, xcol + 8);

    int4 wreg[4][2];  // ring of 4 W-sets; all indices compile-time after unroll

#define DMA_STEP(t, buf)                                                          \
    {                                                                             \
        _Pragma("unroll")                                                         \
        for (int j = 0; j < 4; ++j)                                               \
            __builtin_amdgcn_global_load_lds(                                     \
                (gu32*)(xsrc + (size_t)(t) * 8192 + j * 2048),                    \
                (lu32*)((char*)(&xs[(buf)][0][0]) + wid * 1024 + j * 4096), 16, 0, 0); \
    }

#define STAGE_WW(set, buf)                                                        \
    {                                                                             \
        uint32_t d0[8], d1[8];                                                    \
        decodeW(wreg[(set)][0], d0);                                              \
        decodeW(wreg[(set)][1], d1);                                              \
        *(uint4*)&ww[(buf)][srow][wc0]      = make_uint4(d0[0], d0[1], d0[2], d0[3]); \
        *(uint4*)&ww[(buf)][srow][wc1]      = make_uint4(d0[4], d0[5], d0[6], d0[7]); \
        *(uint4*)&ww[(buf)][srow + 64][wc0] = make_uint4(d1[0], d1[1], d1[2], d1[3]); \
        *(uint4*)&ww[(buf)][srow + 64][wc1] = make_uint4(d1[4], d1[5], d1[6], d1[7]); \
    }

    // ---------- prologue: DMA x(0),x(1); W(0..3) -> regs; decode W(0) -> ww[0] ----------
    DMA_STEP(0, 0);
    __builtin_amdgcn_sched_barrier(0);
    DMA_STEP(1, 1);
    __builtin_amdgcn_sched_barrier(0);
#pragma unroll
    for (int t = 0; t < 4; ++t) {
        wreg[t][0] = *(const int4*)(pg0 + t * WSTRIDE);
        wreg[t][1] = *(const int4*)(pg1 + t * WSTRIDE);
    }
    __builtin_amdgcn_sched_barrier(0);
    STAGE_WW(0, 0);  // implicit vmcnt wait retires DMA(0),DMA(1),W(0)
    __builtin_amdgcn_sched_barrier(0);
    asm volatile("s_waitcnt lgkmcnt(0)" ::: "memory");
    __builtin_amdgcn_s_barrier();
    __builtin_amdgcn_sched_barrier(0);

#pragma unroll
    for (int s = 0; s < NSTEP; ++s) {
        // A: DMA x(s+2) -> xs[(s+2)%3]
        if (s + 2 < NSTEP) DMA_STEP(s + 2, (s + 2) % 3);
        __builtin_amdgcn_sched_barrier(0);
        // B: load W(s+4) -> wreg[(s+4)&3] == wreg[s&3]
        if (s + 4 < NSTEP) {
            wreg[s & 3][0] = *(const int4*)(pg0 + (s + 4) * WSTRIDE);
            wreg[s & 3][1] = *(const int4*)(pg1 + (s + 4) * WSTRIDE);
        }
        __builtin_amdgcn_sched_barrier(0);
        // C: decode W(s+1) (loaded 3+ steps ago) -> ww[(s+1)&1]; interleaves with MFMA
        if (s + 1 < NSTEP) STAGE_WW((s + 1) & 3, (s + 1) & 1);
        // D: MFMA on xs[s%3], ww[s&1]
        __builtin_amdgcn_s_setprio(1);
#pragma unroll
        for (int kk = 0; kk < 2; ++kk) {
            const int kcol = kk * 32 + kgrp;
            bf16x8 af[4], bfr[4];
#pragma unroll
            for (int ar = 0; ar < 4; ++ar) {
                int row = wr * 64 + ar * 16 + arow;
                af[ar] = *(const bf16x8*)&xs[s % 3][row][swz(row, kcol)];
            }
#pragma unroll
            for (int br = 0; br < 4; ++br) {
                int row = wc * 64 + br * 16 + arow;
                bfr[br] = *(const bf16x8*)&ww[s & 1][row][swz(row, kcol)];
            }
#pragma unroll
            for (int ar = 0; ar < 4; ++ar)
#pragma unroll
                for (int br = 0; br < 4; ++br)
                    acc[ar][br] = __builtin_amdgcn_mfma_f32_16x16x32_bf16(
                        af[ar], bfr[br], acc[ar][br], 0, 0, 0);
        }
        __builtin_amdgcn_s_setprio(0);
        // E: counted wait (retire DMA(s+1); keep newer loads in flight) + barrier
        if (s + 1 < NSTEP) {
            __builtin_amdgcn_sched_barrier(0);
            if (s == 0)       asm volatile("s_waitcnt vmcnt(10) lgkmcnt(0)" ::: "memory");
            else if (s <= 11) asm volatile("s_waitcnt vmcnt(8) lgkmcnt(0)" ::: "memory");
            else if (s == 12) asm volatile("s_waitcnt vmcnt(6) lgkmcnt(0)" ::: "memory");
            else if (s == 13) asm volatile("s_waitcnt vmcnt(4) lgkmcnt(0)" ::: "memory");
            else              asm volatile("s_waitcnt vmcnt(0) lgkmcnt(0)" ::: "memory");
            __builtin_amdgcn_s_barrier();
            __builtin_amdgcn_sched_barrier(0);
        }
    }
#undef DMA_STEP
#undef STAGE_WW

    // epilogue: bf16 partial store
    unsigned short* po = pO + ((size_t)ks << 20);
    const int mrow = (lane >> 4) * 4;
#pragma unroll
    for (int ar = 0; ar < 4; ++ar) {
#pragma unroll
        for (int br = 0; br < 4; ++br) {
            int m = wr * 64 + ar * 16 + mrow;
            int n = n0 + wc * 64 + br * 16 + arow;
            unsigned short* pp = po + (size_t)m * OUT_F + n;
#pragma unroll
            for (int j = 0; j < 4; ++j) pp[(size_t)j * OUT_F] = bf16r(acc[ar][br][j]);
        }
    }
}

// ---------------- kernel D: reduce bf16 partials + scale + lora + bias ----------------
__global__ __launch_bounds__(256) void reduce_out(const unsigned short* __restrict__ pO,
                                                  const float* __restrict__ tB,
                                                  const float* __restrict__ scale,
                                                  const float* __restrict__ lora_A,
                                                  const float* __restrict__ bias,
                                                  float* __restrict__ out) {
    __shared__ float ts[4][RANK];
    int nb = blockIdx.x & 15, mg = blockIdx.x >> 4;
    int tid = threadIdx.x;
    int m0 = mg * 4;
    if (tid < 128) {
        int i = tid >> 5, r = tid & 31;
        float s = 0.f;
#pragma unroll
        for (int c = 0; c < LKC; ++c) s += tB[(c * N_TOK + m0 + i) * RANK + r];
        ts[i][r] = s;
    }
    __syncthreads();
    int n = nb * 512 + tid * 2;
    float sc0 = scale[n], sc1 = scale[n + 1];
    float bs0 = bias[n], bs1 = bias[n + 1];
    float4 a0[8], a1[8];
    const float4* ap0 = (const float4*)(lora_A + (size_t)n * RANK);
    const float4* ap1 = (const float4*)(lora_A + (size_t)(n + 1) * RANK);
#pragma unroll
    for (int q = 0; q < 8; ++q) { a0[q] = ap0[q]; a1[q] = ap1[q]; }
#pragma unroll
    for (int i = 0; i < 4; ++i) {
        int m = m0 + i;
        const unsigned short* pp = pO + (size_t)m * OUT_F + n;
        float s0 = 0.f, s1 = 0.f;
#pragma unroll
        for (int c = 0; c < KSPLIT; ++c) {
            uint32_t u = *(const uint32_t*)(pp + ((size_t)c << 20));
            s0 += __uint_as_float(u << 16);
            s1 += __uint_as_float(u & 0xFFFF0000u);
        }
        float l0 = 0.f, l1 = 0.f;
#pragma unroll
        for (int q = 0; q < 8; ++q) {
            float4 tv = *(const float4*)&ts[i][q * 4];
            l0 = fmaf(tv.x, a0[q].x, l0); l0 = fmaf(tv.y, a0[q].y, l0);
            l0 = fmaf(tv.z, a0[q].z, l0); l0 = fmaf(tv.w, a0[q].w, l0);
            l1 = fmaf(tv.x, a1[q].x, l1); l1 = fmaf(tv.y, a1[q].y, l1);
            l1 = fmaf(tv.z, a1[q].z, l1); l1 = fmaf(tv.w, a1[q].w, l1);
        }
        out[(size_t)m * OUT_F + n]     = fmaf(s0, sc0, l0 + bs0);
        out[(size_t)m * OUT_F + n + 1] = fmaf(s1, sc1, l1 + bs1);
    }
}

extern "C" void kernel_launch(void* const* d_in, const int* in_sizes, int n_in,
                              void* d_out, int out_size, void* d_ws, size_t ws_size,
                              hipStream_t stream) {
    const float* x      = (const float*)d_in[0];
    const int*   wp     = (const int*)d_in[1];   // uint8 input -> int32 on device
    const float* scale  = (const float*)d_in[2];
    const float* lora_A = (const float*)d_in[3];
    const float* lora_B = (const float*)d_in[4];
    const float* bias   = (const float*)d_in[5];
    float* out = (float*)d_out;

    char* ws = (char*)d_ws;
    unsigned short* xt = (unsigned short*)(ws + XB_OFF);
    float* tB = (float*)(ws + TB_OFF);
    unsigned short* pO = (unsigned short*)(ws + PO_OFF);

    cvt_x<<<512, 256, 0, stream>>>(x, xt);
    lora_t<<<N_TOK * LKC, 256, 0, stream>>>(x, lora_B, tB);
    ternary_gemm<<<(OUT_F / 128) * KSPLIT, 256, 0, stream>>>(xt, wp, pO);
    reduce_out<<<16 * 32, 256, 0, stream>>>(pO, tB, scale, lora_A, bias, out);
}

// Round 10
// 49.776 us; speedup vs baseline: 1.2317x; 1.0359x over previous
//
#include <hip/hip_runtime.h>
#include <hip/hip_bf16.h>
#include <stdint.h>

typedef float f32x4 __attribute__((ext_vector_type(4)));
typedef __bf16 bf16x8 __attribute__((ext_vector_type(8)));
typedef unsigned short ushort8 __attribute__((ext_vector_type(8)));

#define N_TOK 128
#define OUT_F 8192
#define IN_F  8192
#define RANK  32

#define KSPLIT 8                // main-gemm k-split
#define KB    (IN_F / KSPLIT)   // 1024 per block
#define BK    64
#define NSTEP (KB / BK)         // 16
#define WSTRIDE 16              // ints per step per W row (BK/4)
#define LKC   4                 // lora-t k-chunks

// workspace layout (bytes)
#define XB_OFF 0
#define TB_OFF ((size_t)N_TOK * IN_F * 2)                      // 2 MiB fragment-ordered bf16 x
#define PO_OFF (TB_OFF + (size_t)LKC * N_TOK * RANK * 4)       // + 64 KiB t-partials
// pO: KSPLIT * 128 * 8192 bf16 = 16 MiB

__device__ __forceinline__ unsigned short bf16r(float f) {
    uint32_t u = __float_as_uint(f);
    return (unsigned short)((u + 0x7FFFu + ((u >> 16) & 1u)) >> 16);
}

__device__ __forceinline__ int swz(int row, int col) { return col ^ ((row & 7) << 3); }

// ---------------- kernel A: x fp32 -> bf16 in MFMA-fragment record order ----------------
// record rec = (sblk*2 + kk)*8 + ar16  (1 KiB each: 64 lanes x 16 B).
// lane l holds X[ar16*16 + (l&15)][sblk*64 + kk*32 + (l>>4)*8 .. +8].
// A-fragment load in the GEMM = one coalesced 16 B/lane read of a record.
__global__ __launch_bounds__(256) void cvt_x(const float* __restrict__ x,
                                             unsigned short* __restrict__ xt) {
    size_t f = (size_t)blockIdx.x * 256 + threadIdx.x;  // 0..131071 (16-B chunks)
    int lane = (int)(f & 63);
    int rec  = (int)(f >> 6);          // 0..2047
    int ar16 = rec & 7;
    int kk   = (rec >> 3) & 1;
    int sblk = rec >> 4;               // 0..127
    int row = ar16 * 16 + (lane & 15);
    int k   = sblk * 64 + kk * 32 + (lane >> 4) * 8;
    const float4* sp = (const float4*)(x + (size_t)row * IN_F + k);
    float4 a = sp[0], b = sp[1];
    ushort8 o;
    o[0] = bf16r(a.x); o[1] = bf16r(a.y); o[2] = bf16r(a.z); o[3] = bf16r(a.w);
    o[4] = bf16r(b.x); o[5] = bf16r(b.y); o[6] = bf16r(b.z); o[7] = bf16r(b.w);
    *(ushort8*)(xt + f * 8) = o;
}

// ---------------- kernel B: t-partials = x @ lora_B^T, coalesced ----------------
__global__ __launch_bounds__(256) void lora_t(const float* __restrict__ x,
                                              const float* __restrict__ lb,
                                              float* __restrict__ tB) {
    __shared__ float ts[256][33];
    __shared__ float ps[8][32];
    const int m = blockIdx.x >> 2, kc = blockIdx.x & 3;
    const int tid = threadIdx.x;
    const int c0 = kc * 2048 + tid * 8;
    float4 xv0 = *(const float4*)(x + (size_t)m * IN_F + c0);
    float4 xv1 = *(const float4*)(x + (size_t)m * IN_F + c0 + 4);
#pragma unroll
    for (int r = 0; r < RANK; ++r) {
        const float4* bp = (const float4*)(lb + (size_t)r * IN_F + c0);
        float4 b0 = bp[0], b1 = bp[1];
        float s = xv0.x * b0.x + xv0.y * b0.y + xv0.z * b0.z + xv0.w * b0.w +
                  xv1.x * b1.x + xv1.y * b1.y + xv1.z * b1.z + xv1.w * b1.w;
        ts[tid][r] = s;
    }
    __syncthreads();
    {
        int g = tid >> 5, r = tid & 31;
        float s = 0.f;
        for (int j = 0; j < 32; ++j) s += ts[g * 32 + j][r];
        ps[g][r] = s;
    }
    __syncthreads();
    if (tid < 32) {
        float s = 0.f;
#pragma unroll
        for (int g = 0; g < 8; ++g) s += ps[g][tid];
        tB[(kc * N_TOK + m) * RANK + tid] = s;
    }
}

// ---------------- decode: 16 ternary codes (4 widened ints) -> 8 dwords of bf16 pairs ----------------
__device__ __forceinline__ void decodeW(int4 v, uint32_t d[8]) {
    uint32_t p = (uint32_t)v.x | ((uint32_t)v.y << 8) |
                 ((uint32_t)v.z << 16) | ((uint32_t)v.w << 24);
    const uint32_t HI = 0x403F00BFu;
    const uint32_t LO = 0x00800080u;
#pragma unroll
    for (int j = 0; j < 8; ++j) {
        uint32_t c0 = (p >> (4 * j)) & 3u;
        uint32_t c1 = (p >> (4 * j + 2)) & 3u;
        uint32_t t = c0 | (c1 << 16);
        uint32_t sel = (t | (t << 8)) + 0x04000400u;
        d[j] = __builtin_amdgcn_perm(HI, LO, sel);
    }
}

// ---------------- kernel C: ternary GEMM — A direct from L2 (fragment records),
// W decoded into a single 16 KiB LDS buffer; barriers drain ONLY lgkmcnt.
// grid = 64 n-tiles * KSPLIT(8) = 512 blocks, 256 threads (4 waves, 2x2 of 64x64).
__global__ __launch_bounds__(256) void ternary_gemm(const unsigned short* __restrict__ xt,
                                                    const int* __restrict__ wp,
                                                    unsigned short* __restrict__ pO) {
    __shared__ unsigned short ww[128][64];  // 16 KiB, single-buffered, XOR-swizzled
    const int tid = threadIdx.x;
    const int nb = blockIdx.x >> 3;
    const int ks = blockIdx.x & 7;
    const int n0 = nb * 128;
    const int lane = tid & 63;
    const int wid = tid >> 6;
    const int wr = wid >> 1, wc = wid & 1;

    const int srow = tid >> 2;
    const int xcol = (tid & 3) * 16;
    const int* pg0 = wp + (size_t)(n0 + srow) * (IN_F / 4) + ks * (KB / 4) + (tid & 3) * 4;
    const int* pg1 = pg0 + (size_t)64 * (IN_F / 4);

    const int arow = lane & 15;
    const int kgrp = (lane >> 4) * 8;
    const int wc0 = swz(srow, xcol), wc1 = swz(srow, xcol + 8);

    // A record base: rec(s,kk,ar16) = ((ks*NSTEP+s)*2 + kk)*8 + ar16; 512 ushorts each
    const unsigned short* abase = xt + ((size_t)(ks * NSTEP) * 16) * 512 + lane * 8;
#define LDA(s_, kk_, ar_) \
    (*(const bf16x8*)(abase + ((size_t)((s_)*16 + (kk_)*8 + (wr * 4 + (ar_)))) * 512))

    f32x4 acc[4][4];
#pragma unroll
    for (int i = 0; i < 4; ++i)
#pragma unroll
        for (int j = 0; j < 4; ++j) acc[i][j] = (f32x4){0.f, 0.f, 0.f, 0.f};

    bf16x8 aX[4][2], aY[4][2];
    int4 wP[2][2];  // [parity][row-half] packed W, 2-step-ahead ring

    // ---------- prologue ----------
#pragma unroll
    for (int ar = 0; ar < 4; ++ar) {
        aX[ar][0] = LDA(0, 0, ar);
        aX[ar][1] = LDA(0, 1, ar);
    }
    wP[0][0] = *(const int4*)(pg0);
    wP[0][1] = *(const int4*)(pg1);
    wP[1][0] = *(const int4*)(pg0 + WSTRIDE);
    wP[1][1] = *(const int4*)(pg1 + WSTRIDE);
    {
        uint32_t d0[8], d1[8];
        decodeW(wP[0][0], d0);   // compiler waits W(0) (+A ahead of it in FIFO)
        decodeW(wP[0][1], d1);
        *(uint4*)&ww[srow][wc0]      = make_uint4(d0[0], d0[1], d0[2], d0[3]);
        *(uint4*)&ww[srow][wc1]      = make_uint4(d0[4], d0[5], d0[6], d0[7]);
        *(uint4*)&ww[srow + 64][wc0] = make_uint4(d1[0], d1[1], d1[2], d1[3]);
        *(uint4*)&ww[srow + 64][wc1] = make_uint4(d1[4], d1[5], d1[6], d1[7]);
    }
    wP[0][0] = *(const int4*)(pg0 + 2 * WSTRIDE);   // W(2) -> parity 0
    wP[0][1] = *(const int4*)(pg1 + 2 * WSTRIDE);
    __builtin_amdgcn_sched_barrier(0);
    asm volatile("s_waitcnt lgkmcnt(0)" ::: "memory");
    __builtin_amdgcn_s_barrier();
    __builtin_amdgcn_sched_barrier(0);

#pragma unroll
    for (int s = 0; s < NSTEP; ++s) {
        bf16x8 (*aCur)[2] = (s & 1) ? aY : aX;
        bf16x8 (*aNxt)[2] = (s & 1) ? aX : aY;
        // 1. B-fragment reads from ww(s)
        bf16x8 bfr[2][4];
#pragma unroll
        for (int kk = 0; kk < 2; ++kk)
#pragma unroll
            for (int br = 0; br < 4; ++br) {
                int row = wc * 64 + br * 16 + arow;
                bfr[kk][br] = *(const bf16x8*)&ww[row][swz(row, kk * 32 + kgrp)];
            }
        // 2. MFMA by ar-group; prefetch A(s+1) per group (rides all barriers)
#pragma unroll
        for (int ar = 0; ar < 4; ++ar) {
#pragma unroll
            for (int kk = 0; kk < 2; ++kk)
#pragma unroll
                for (int br = 0; br < 4; ++br)
                    acc[ar][br] = __builtin_amdgcn_mfma_f32_16x16x32_bf16(
                        aCur[ar][kk], bfr[kk][br], acc[ar][br], 0, 0, 0);
            if (s + 1 < NSTEP) {
                aNxt[ar][0] = LDA(s + 1, 0, ar);
                aNxt[ar][1] = LDA(s + 1, 1, ar);
            }
        }
        if (s + 1 < NSTEP) {
            // 3. decode W(s+1) (in regs for ~2 steps; vmcnt wait counted, A-loads newer)
            uint32_t d0[8], d1[8];
            decodeW(wP[(s + 1) & 1][0], d0);
            decodeW(wP[(s + 1) & 1][1], d1);
            // 4. barrier: everyone finished reading ww(s) (bfr already in regs)
            __builtin_amdgcn_sched_barrier(0);
            __builtin_amdgcn_s_barrier();
            __builtin_amdgcn_sched_barrier(0);
            // 5. write ww(s+1); issue W(s+2) into freed parity slot
            *(uint4*)&ww[srow][wc0]      = make_uint4(d0[0], d0[1], d0[2], d0[3]);
            *(uint4*)&ww[srow][wc1]      = make_uint4(d0[4], d0[5], d0[6], d0[7]);
            *(uint4*)&ww[srow + 64][wc0] = make_uint4(d1[0], d1[1], d1[2], d1[3]);
            *(uint4*)&ww[srow + 64][wc1] = make_uint4(d1[4], d1[5], d1[6], d1[7]);
            if (s + 2 < NSTEP) {
                wP[s & 1][0] = *(const int4*)(pg0 + (s + 2) * WSTRIDE);
                wP[s & 1][1] = *(const int4*)(pg1 + (s + 2) * WSTRIDE);
            }
            // 6. lgkm-only drain + barrier: ww(s+1) visible; vmem rides
            __builtin_amdgcn_sched_barrier(0);
            asm volatile("s_waitcnt lgkmcnt(0)" ::: "memory");
            __builtin_amdgcn_s_barrier();
            __builtin_amdgcn_sched_barrier(0);
        }
    }
#undef LDA

    // epilogue: bf16 partial store
    unsigned short* po = pO + ((size_t)ks << 20);
    const int mrow = (lane >> 4) * 4;
#pragma unroll
    for (int ar = 0; ar < 4; ++ar) {
#pragma unroll
        for (int br = 0; br < 4; ++br) {
            int m = wr * 64 + ar * 16 + mrow;
            int n = n0 + wc * 64 + br * 16 + arow;
            unsigned short* pp = po + (size_t)m * OUT_F + n;
#pragma unroll
            for (int j = 0; j < 4; ++j) pp[(size_t)j * OUT_F] = bf16r(acc[ar][br][j]);
        }
    }
}

// ---------------- kernel D: reduce bf16 partials + scale + lora + bias ----------------
// grid = 16 nb * 32 mg = 512 blocks; thread: 2 consecutive n, 4 m's
__global__ __launch_bounds__(256) void reduce_out(const unsigned short* __restrict__ pO,
                                                  const float* __restrict__ tB,
                                                  const float* __restrict__ scale,
                                                  const float* __restrict__ lora_A,
                                                  const float* __restrict__ bias,
                                                  float* __restrict__ out) {
    __shared__ float ts[4][RANK];
    int nb = blockIdx.x & 15, mg = blockIdx.x >> 4;
    int tid = threadIdx.x;
    int m0 = mg * 4;
    if (tid < 128) {
        int i = tid >> 5, r = tid & 31;
        float s = 0.f;
#pragma unroll
        for (int c = 0; c < LKC; ++c) s += tB[(c * N_TOK + m0 + i) * RANK + r];
        ts[i][r] = s;
    }
    __syncthreads();
    int n = nb * 512 + tid * 2;
    float sc0 = scale[n], sc1 = scale[n + 1];
    float bs0 = bias[n], bs1 = bias[n + 1];
    float4 a0[8], a1[8];
    const float4* ap0 = (const float4*)(lora_A + (size_t)n * RANK);
    const float4* ap1 = (const float4*)(lora_A + (size_t)(n + 1) * RANK);
#pragma unroll
    for (int q = 0; q < 8; ++q) { a0[q] = ap0[q]; a1[q] = ap1[q]; }
#pragma unroll
    for (int i = 0; i < 4; ++i) {
        int m = m0 + i;
        const unsigned short* pp = pO + (size_t)m * OUT_F + n;
        float s0 = 0.f, s1 = 0.f;
#pragma unroll
        for (int c = 0; c < KSPLIT; ++c) {
            uint32_t u = *(const uint32_t*)(pp + ((size_t)c << 20));
            s0 += __uint_as_float(u << 16);
            s1 += __uint_as_float(u & 0xFFFF0000u);
        }
        float l0 = 0.f, l1 = 0.f;
#pragma unroll
        for (int q = 0; q < 8; ++q) {
            float4 tv = *(const float4*)&ts[i][q * 4];
            l0 = fmaf(tv.x, a0[q].x, l0); l0 = fmaf(tv.y, a0[q].y, l0);
            l0 = fmaf(tv.z, a0[q].z, l0); l0 = fmaf(tv.w, a0[q].w, l0);
            l1 = fmaf(tv.x, a1[q].x, l1); l1 = fmaf(tv.y, a1[q].y, l1);
            l1 = fmaf(tv.z, a1[q].z, l1); l1 = fmaf(tv.w, a1[q].w, l1);
        }
        out[(size_t)m * OUT_F + n]     = fmaf(s0, sc0, l0 + bs0);
        out[(size_t)m * OUT_F + n + 1] = fmaf(s1, sc1, l1 + bs1);
    }
}

extern "C" void kernel_launch(void* const* d_in, const int* in_sizes, int n_in,
                              void* d_out, int out_size, void* d_ws, size_t ws_size,
                              hipStream_t stream) {
    const float* x      = (const float*)d_in[0];
    const int*   wp     = (const int*)d_in[1];   // uint8 input -> int32 on device
    const float* scale  = (const float*)d_in[2];
    const float* lora_A = (const float*)d_in[3];
    const float* lora_B = (const float*)d_in[4];
    const float* bias   = (const float*)d_in[5];
    float* out = (float*)d_out;

    char* ws = (char*)d_ws;
    unsigned short* xt = (unsigned short*)(ws + XB_OFF);
    float* tB = (float*)(ws + TB_OFF);
    unsigned short* pO = (unsigned short*)(ws + PO_OFF);

    cvt_x<<<512, 256, 0, stream>>>(x, xt);
    lora_t<<<N_TOK * LKC, 256, 0, stream>>>(x, lora_B, tB);
    ternary_gemm<<<(OUT_F / 128) * KSPLIT, 256, 0, stream>>>(xt, wp, pO);
    reduce_out<<<16 * 32, 256, 0, stream>>>(pO, tB, scale, lora_A, bias, out);
}

// Round 11
// 49.363 us; speedup vs baseline: 1.2420x; 1.0084x over previous
//
#include <hip/hip_runtime.h>
#include <hip/hip_bf16.h>
#include <stdint.h>

typedef float f32x4 __attribute__((ext_vector_type(4)));
typedef __bf16 bf16x8 __attribute__((ext_vector_type(8)));
typedef unsigned short ushort8 __attribute__((ext_vector_type(8)));

#define N_TOK 128
#define OUT_F 8192
#define IN_F  8192
#define RANK  32

#define KSPLIT 8                // main-gemm k-split
#define KB    (IN_F / KSPLIT)   // 1024 per block
#define BK    64
#define NSTEP (KB / BK)         // 16
#define WSTRIDE 16              // ints per step per W row (BK/4)
#define LKC   4                 // lora-t k-chunks

// workspace layout (bytes)
#define XB_OFF 0
#define TB_OFF ((size_t)N_TOK * IN_F * 2)                      // 2 MiB fragment-ordered bf16 x
#define PO_OFF (TB_OFF + (size_t)LKC * N_TOK * RANK * 4)       // + 64 KiB t-partials
// pO: KSPLIT * 128 * 8192 bf16 = 16 MiB

__device__ __forceinline__ unsigned short bf16r(float f) {
    uint32_t u = __float_as_uint(f);
    return (unsigned short)((u + 0x7FFFu + ((u >> 16) & 1u)) >> 16);
}

__device__ __forceinline__ int swz(int row, int col) { return col ^ ((row & 7) << 3); }

// ---------------- kernel A: x fp32 -> bf16 in MFMA-fragment record order ----------------
// record rec = (sblk*2 + kk)*8 + ar16  (1 KiB each: 64 lanes x 16 B).
// lane l holds X[ar16*16 + (l&15)][sblk*64 + kk*32 + (l>>4)*8 .. +8].
// A-fragment load in the GEMM = one coalesced 16 B/lane read of a record.
__global__ __launch_bounds__(256) void cvt_x(const float* __restrict__ x,
                                             unsigned short* __restrict__ xt) {
    size_t f = (size_t)blockIdx.x * 256 + threadIdx.x;  // 0..131071 (16-B chunks)
    int lane = (int)(f & 63);
    int rec  = (int)(f >> 6);          // 0..2047
    int ar16 = rec & 7;
    int kk   = (rec >> 3) & 1;
    int sblk = rec >> 4;               // 0..127
    int row = ar16 * 16 + (lane & 15);
    int k   = sblk * 64 + kk * 32 + (lane >> 4) * 8;
    const float4* sp = (const float4*)(x + (size_t)row * IN_F + k);
    float4 a = sp[0], b = sp[1];
    ushort8 o;
    o[0] = bf16r(a.x); o[1] = bf16r(a.y); o[2] = bf16r(a.z); o[3] = bf16r(a.w);
    o[4] = bf16r(b.x); o[5] = bf16r(b.y); o[6] = bf16r(b.z); o[7] = bf16r(b.w);
    *(ushort8*)(xt + f * 8) = o;
}

// ---------------- kernel B: t-partials = x @ lora_B^T, coalesced ----------------
__global__ __launch_bounds__(256) void lora_t(const float* __restrict__ x,
                                              const float* __restrict__ lb,
                                              float* __restrict__ tB) {
    __shared__ float ts[256][33];
    __shared__ float ps[8][32];
    const int m = blockIdx.x >> 2, kc = blockIdx.x & 3;
    const int tid = threadIdx.x;
    const int c0 = kc * 2048 + tid * 8;
    float4 xv0 = *(const float4*)(x + (size_t)m * IN_F + c0);
    float4 xv1 = *(const float4*)(x + (size_t)m * IN_F + c0 + 4);
#pragma unroll
    for (int r = 0; r < RANK; ++r) {
        const float4* bp = (const float4*)(lb + (size_t)r * IN_F + c0);
        float4 b0 = bp[0], b1 = bp[1];
        float s = xv0.x * b0.x + xv0.y * b0.y + xv0.z * b0.z + xv0.w * b0.w +
                  xv1.x * b1.x + xv1.y * b1.y + xv1.z * b1.z + xv1.w * b1.w;
        ts[tid][r] = s;
    }
    __syncthreads();
    {
        int g = tid >> 5, r = tid & 31;
        float s = 0.f;
        for (int j = 0; j < 32; ++j) s += ts[g * 32 + j][r];
        ps[g][r] = s;
    }
    __syncthreads();
    if (tid < 32) {
        float s = 0.f;
#pragma unroll
        for (int g = 0; g < 8; ++g) s += ps[g][tid];
        tB[(kc * N_TOK + m) * RANK + tid] = s;
    }
}

// ---------------- decode: 16 ternary codes (4 widened ints) -> 8 dwords of bf16 pairs ----------------
__device__ __forceinline__ void decodeW(int4 v, uint32_t d[8]) {
    uint32_t p = (uint32_t)v.x | ((uint32_t)v.y << 8) |
                 ((uint32_t)v.z << 16) | ((uint32_t)v.w << 24);
    const uint32_t HI = 0x403F00BFu;
    const uint32_t LO = 0x00800080u;
#pragma unroll
    for (int j = 0; j < 8; ++j) {
        uint32_t c0 = (p >> (4 * j)) & 3u;
        uint32_t c1 = (p >> (4 * j + 2)) & 3u;
        uint32_t t = c0 | (c1 << 16);
        uint32_t sel = (t | (t << 8)) + 0x04000400u;
        d[j] = __builtin_amdgcn_perm(HI, LO, sel);
    }
}

// ---------------- kernel C: ternary GEMM — A direct from L2 (fragment records),
// W decoded into a single 16 KiB LDS buffer; barriers drain ONLY lgkmcnt.
// grid = 64 n-tiles * KSPLIT(8) = 512 blocks, 256 threads (4 waves, 2x2 of 64x64).
__global__ __launch_bounds__(256) void ternary_gemm(const unsigned short* __restrict__ xt,
                                                    const int* __restrict__ wp,
                                                    unsigned short* __restrict__ pO) {
    __shared__ unsigned short ww[128][64];  // 16 KiB, single-buffered, XOR-swizzled
    const int tid = threadIdx.x;
    const int nb = blockIdx.x >> 3;
    const int ks = blockIdx.x & 7;
    const int n0 = nb * 128;
    const int lane = tid & 63;
    const int wid = tid >> 6;
    const int wr = wid >> 1, wc = wid & 1;

    const int srow = tid >> 2;
    const int xcol = (tid & 3) * 16;
    const int* pg0 = wp + (size_t)(n0 + srow) * (IN_F / 4) + ks * (KB / 4) + (tid & 3) * 4;
    const int* pg1 = pg0 + (size_t)64 * (IN_F / 4);

    const int arow = lane & 15;
    const int kgrp = (lane >> 4) * 8;
    const int wc0 = swz(srow, xcol), wc1 = swz(srow, xcol + 8);

    // A record base: rec(s,kk,ar16) = ((ks*NSTEP+s)*2 + kk)*8 + ar16; 512 ushorts each
    const unsigned short* abase = xt + ((size_t)(ks * NSTEP) * 16) * 512 + lane * 8;
#define LDA(s_, kk_, ar_) \
    (*(const bf16x8*)(abase + ((size_t)((s_)*16 + (kk_)*8 + (wr * 4 + (ar_)))) * 512))

    f32x4 acc[4][4];
#pragma unroll
    for (int i = 0; i < 4; ++i)
#pragma unroll
        for (int j = 0; j < 4; ++j) acc[i][j] = (f32x4){0.f, 0.f, 0.f, 0.f};

    bf16x8 aX[4][2], aY[4][2];
    int4 wP[2][2];  // [parity][row-half] packed W, 2-step-ahead ring

    // ---------- prologue ----------
#pragma unroll
    for (int ar = 0; ar < 4; ++ar) {
        aX[ar][0] = LDA(0, 0, ar);
        aX[ar][1] = LDA(0, 1, ar);
    }
    wP[0][0] = *(const int4*)(pg0);
    wP[0][1] = *(const int4*)(pg1);
    wP[1][0] = *(const int4*)(pg0 + WSTRIDE);
    wP[1][1] = *(const int4*)(pg1 + WSTRIDE);
    {
        uint32_t d0[8], d1[8];
        decodeW(wP[0][0], d0);   // compiler waits W(0) (+A ahead of it in FIFO)
        decodeW(wP[0][1], d1);
        *(uint4*)&ww[srow][wc0]      = make_uint4(d0[0], d0[1], d0[2], d0[3]);
        *(uint4*)&ww[srow][wc1]      = make_uint4(d0[4], d0[5], d0[6], d0[7]);
        *(uint4*)&ww[srow + 64][wc0] = make_uint4(d1[0], d1[1], d1[2], d1[3]);
        *(uint4*)&ww[srow + 64][wc1] = make_uint4(d1[4], d1[5], d1[6], d1[7]);
    }
    wP[0][0] = *(const int4*)(pg0 + 2 * WSTRIDE);   // W(2) -> parity 0
    wP[0][1] = *(const int4*)(pg1 + 2 * WSTRIDE);
    __builtin_amdgcn_sched_barrier(0);
    asm volatile("s_waitcnt lgkmcnt(0)" ::: "memory");
    __builtin_amdgcn_s_barrier();
    __builtin_amdgcn_sched_barrier(0);

#pragma unroll
    for (int s = 0; s < NSTEP; ++s) {
        bf16x8 (*aCur)[2] = (s & 1) ? aY : aX;
        bf16x8 (*aNxt)[2] = (s & 1) ? aX : aY;
        // 1. B-fragment reads from ww(s)
        bf16x8 bfr[2][4];
#pragma unroll
        for (int kk = 0; kk < 2; ++kk)
#pragma unroll
            for (int br = 0; br < 4; ++br) {
                int row = wc * 64 + br * 16 + arow;
                bfr[kk][br] = *(const bf16x8*)&ww[row][swz(row, kk * 32 + kgrp)];
            }
        // 2. MFMA by ar-group; prefetch A(s+1) per group (rides all barriers)
#pragma unroll
        for (int ar = 0; ar < 4; ++ar) {
#pragma unroll
            for (int kk = 0; kk < 2; ++kk)
#pragma unroll
                for (int br = 0; br < 4; ++br)
                    acc[ar][br] = __builtin_amdgcn_mfma_f32_16x16x32_bf16(
                        aCur[ar][kk], bfr[kk][br], acc[ar][br], 0, 0, 0);
            if (s + 1 < NSTEP) {
                aNxt[ar][0] = LDA(s + 1, 0, ar);
                aNxt[ar][1] = LDA(s + 1, 1, ar);
            }
        }
        if (s + 1 < NSTEP) {
            // 3. decode W(s+1) (in regs for ~2 steps; vmcnt wait counted, A-loads newer)
            uint32_t d0[8], d1[8];
            decodeW(wP[(s + 1) & 1][0], d0);
            decodeW(wP[(s + 1) & 1][1], d1);
            // 4. barrier: everyone finished reading ww(s) (bfr already in regs)
            __builtin_amdgcn_sched_barrier(0);
            __builtin_amdgcn_s_barrier();
            __builtin_amdgcn_sched_barrier(0);
            // 5. write ww(s+1); issue W(s+2) into freed parity slot
            *(uint4*)&ww[srow][wc0]      = make_uint4(d0[0], d0[1], d0[2], d0[3]);
            *(uint4*)&ww[srow][wc1]      = make_uint4(d0[4], d0[5], d0[6], d0[7]);
            *(uint4*)&ww[srow + 64][wc0] = make_uint4(d1[0], d1[1], d1[2], d1[3]);
            *(uint4*)&ww[srow + 64][wc1] = make_uint4(d1[4], d1[5], d1[6], d1[7]);
            if (s + 2 < NSTEP) {
                wP[s & 1][0] = *(const int4*)(pg0 + (s + 2) * WSTRIDE);
                wP[s & 1][1] = *(const int4*)(pg1 + (s + 2) * WSTRIDE);
            }
            // 6. lgkm-only drain + barrier: ww(s+1) visible; vmem rides
            __builtin_amdgcn_sched_barrier(0);
            asm volatile("s_waitcnt lgkmcnt(0)" ::: "memory");
            __builtin_amdgcn_s_barrier();
            __builtin_amdgcn_sched_barrier(0);
        }
    }
#undef LDA

    // epilogue: bf16 partial store
    unsigned short* po = pO + ((size_t)ks << 20);
    const int mrow = (lane >> 4) * 4;
#pragma unroll
    for (int ar = 0; ar < 4; ++ar) {
#pragma unroll
        for (int br = 0; br < 4; ++br) {
            int m = wr * 64 + ar * 16 + mrow;
            int n = n0 + wc * 64 + br * 16 + arow;
            unsigned short* pp = po + (size_t)m * OUT_F + n;
#pragma unroll
            for (int j = 0; j < 4; ++j) pp[(size_t)j * OUT_F] = bf16r(acc[ar][br][j]);
        }
    }
}

// ---------------- kernel D: reduce bf16 partials + scale + lora + bias ----------------
// grid = 16 nb * 32 mg = 512 blocks; thread: 2 consecutive n, 4 m's
__global__ __launch_bounds__(256) void reduce_out(const unsigned short* __restrict__ pO,
                                                  const float* __restrict__ tB,
                                                  const float* __restrict__ scale,
                                                  const float* __restrict__ lora_A,
                                                  const float* __restrict__ bias,
                                                  float* __restrict__ out) {
    __shared__ float ts[4][RANK];
    int nb = blockIdx.x & 15, mg = blockIdx.x >> 4;
    int tid = threadIdx.x;
    int m0 = mg * 4;
    if (tid < 128) {
        int i = tid >> 5, r = tid & 31;
        float s = 0.f;
#pragma unroll
        for (int c = 0; c < LKC; ++c) s += tB[(c * N_TOK + m0 + i) * RANK + r];
        ts[i][r] = s;
    }
    __syncthreads();
    int n = nb * 512 + tid * 2;
    float sc0 = scale[n], sc1 = scale[n + 1];
    float bs0 = bias[n], bs1 = bias[n + 1];
    float4 a0[8], a1[8];
    const float4* ap0 = (const float4*)(lora_A + (size_t)n * RANK);
    const float4* ap1 = (const float4*)(lora_A + (size_t)(n + 1) * RANK);
#pragma unroll
    for (int q = 0; q < 8; ++q) { a0[q] = ap0[q]; a1[q] = ap1[q]; }
#pragma unroll
    for (int i = 0; i < 4; ++i) {
        int m = m0 + i;
        const unsigned short* pp = pO + (size_t)m * OUT_F + n;
        float s0 = 0.f, s1 = 0.f;
#pragma unroll
        for (int c = 0; c < KSPLIT; ++c) {
            uint32_t u = *(const uint32_t*)(pp + ((size_t)c << 20));
            s0 += __uint_as_float(u << 16);
            s1 += __uint_as_float(u & 0xFFFF0000u);
        }
        float l0 = 0.f, l1 = 0.f;
#pragma unroll
        for (int q = 0; q < 8; ++q) {
            float4 tv = *(const float4*)&ts[i][q * 4];
            l0 = fmaf(tv.x, a0[q].x, l0); l0 = fmaf(tv.y, a0[q].y, l0);
            l0 = fmaf(tv.z, a0[q].z, l0); l0 = fmaf(tv.w, a0[q].w, l0);
            l1 = fmaf(tv.x, a1[q].x, l1); l1 = fmaf(tv.y, a1[q].y, l1);
            l1 = fmaf(tv.z, a1[q].z, l1); l1 = fmaf(tv.w, a1[q].w, l1);
        }
        out[(size_t)m * OUT_F + n]     = fmaf(s0, sc0, l0 + bs0);
        out[(size_t)m * OUT_F + n + 1] = fmaf(s1, sc1, l1 + bs1);
    }
}

extern "C" void kernel_launch(void* const* d_in, const int* in_sizes, int n_in,
                              void* d_out, int out_size, void* d_ws, size_t ws_size,
                              hipStream_t stream) {
    const float* x      = (const float*)d_in[0];
    const int*   wp     = (const int*)d_in[1];   // uint8 input -> int32 on device
    const float* scale  = (const float*)d_in[2];
    const float* lora_A = (const float*)d_in[3];
    const float* lora_B = (const float*)d_in[4];
    const float* bias   = (const float*)d_in[5];
    float* out = (float*)d_out;

    char* ws = (char*)d_ws;
    unsigned short* xt = (unsigned short*)(ws + XB_OFF);
    float* tB = (float*)(ws + TB_OFF);
    unsigned short* pO = (unsigned short*)(ws + PO_OFF);

    cvt_x<<<512, 256, 0, stream>>>(x, xt);
    lora_t<<<N_TOK * LKC, 256, 0, stream>>>(x, lora_B, tB);
    ternary_gemm<<<(OUT_F / 128) * KSPLIT, 256, 0, stream>>>(xt, wp, pO);
    reduce_out<<<16 * 32, 256, 0, stream>>>(pO, tB, scale, lora_A, bias, out);
}